// Round 7
// baseline (6549.315 us; speedup 1.0000x reference)
//
#include <hip/hip_runtime.h>
#include <stdint.h>
#include <cstdio>

#define B   256
#define T   1024
#define FIN 64
#define H   128
#define G4  512   // 4*H

typedef float vf32 __attribute__((ext_vector_type(32)));
typedef float vf16 __attribute__((ext_vector_type(16)));

#define RL(v, q) __int_as_float(__builtin_amdgcn_readlane(__float_as_int(v), (q)))

// 128-float register bank in four SSA vectors. Literal indices only.
#define WG(n)    ((n) < 32 ? wa[(n) & 31] : (n) < 64 ? wb[(n) & 31] : (n) < 96 ? wc[(n) & 31] : wd[(n) & 31])
#define WS(n, v) do { if ((n) < 32) wa[(n) & 31] = (v); else if ((n) < 64) wb[(n) & 31] = (v); \
                      else if ((n) < 96) wc[(n) & 31] = (v); else wd[(n) & 31] = (v); } while (0)
// 64-float bank (two vectors)
#define WG2(n)    ((n) < 32 ? wa[(n) & 31] : wb[(n) & 31])
#define WS2(n, v) do { if ((n) < 32) wa[(n) & 31] = (v); else wb[(n) & 31] = (v); } while (0)

// ----------------------------------------------------------------------------
// prep: transpose W_ih -> WT[k][j], bias sums, zero recurrent states
// ----------------------------------------------------------------------------
__global__ void prep_kernel(const float* __restrict__ W_ih0,
                            const float* __restrict__ b_ih0, const float* __restrict__ b_hh0,
                            const float* __restrict__ W_ih1,
                            const float* __restrict__ b_ih1, const float* __restrict__ b_hh1,
                            float* __restrict__ WT0, float* __restrict__ WT1,
                            float* __restrict__ bsum0, float* __restrict__ bsum1,
                            float* __restrict__ states /* 4*B*H */)
{
    int idx = blockIdx.x * blockDim.x + threadIdx.x;
    int n   = gridDim.x * blockDim.x;
    for (int i = idx; i < H * G4; i += n) { int k = i / G4, j = i % G4; WT1[i] = W_ih1[j * H + k]; }
    for (int i = idx; i < FIN * G4; i += n) { int k = i / G4, j = i % G4; WT0[i] = W_ih0[j * FIN + k]; }
    for (int i = idx; i < G4; i += n) { bsum0[i] = b_ih0[i] + b_hh0[i]; bsum1[i] = b_ih1[i] + b_hh1[i]; }
    for (int i = idx; i < 4 * B * H; i += n) states[i] = 0.f;
}

// ----------------------------------------------------------------------------
// gx GEMM: gx[tcl][b][j] = bias[j] + sum_k X[b, toff+tcl, k] * WT[k][j]
// 512 threads = 512 columns; 16 rows per block. K in 64-wide halves, weights
// loaded VOLATILE (un-rematerializable -> must stay in registers; R4-R6
// showed the backend otherwise re-issues the loads every use).
// ----------------------------------------------------------------------------
#define CLDW(n) WS2(n, wp0[(long)(n) * G4]);
#define CLDW4(n)  CLDW(n) CLDW((n)+1) CLDW((n)+2) CLDW((n)+3)
#define CLDW16(n) CLDW4(n) CLDW4((n)+4) CLDW4((n)+8) CLDW4((n)+12)
#define CLDW64    CLDW16(0) CLDW16(16) CLDW16(32) CLDW16(48)

#define GK4R(k, r0) { \
    float4 v0 = *(const float4*)(x0 + (k)); \
    float4 v1 = *(const float4*)(x1 + (k)); \
    float4 v2 = *(const float4*)(x2 + (k)); \
    float4 v3 = *(const float4*)(x3 + (k)); \
    acc[(r0)+0] = fmaf(v0.x, WG2(k), acc[(r0)+0]); acc[(r0)+0] = fmaf(v0.y, WG2((k)+1), acc[(r0)+0]); \
    acc[(r0)+0] = fmaf(v0.z, WG2((k)+2), acc[(r0)+0]); acc[(r0)+0] = fmaf(v0.w, WG2((k)+3), acc[(r0)+0]); \
    acc[(r0)+1] = fmaf(v1.x, WG2(k), acc[(r0)+1]); acc[(r0)+1] = fmaf(v1.y, WG2((k)+1), acc[(r0)+1]); \
    acc[(r0)+1] = fmaf(v1.z, WG2((k)+2), acc[(r0)+1]); acc[(r0)+1] = fmaf(v1.w, WG2((k)+3), acc[(r0)+1]); \
    acc[(r0)+2] = fmaf(v2.x, WG2(k), acc[(r0)+2]); acc[(r0)+2] = fmaf(v2.y, WG2((k)+1), acc[(r0)+2]); \
    acc[(r0)+2] = fmaf(v2.z, WG2((k)+2), acc[(r0)+2]); acc[(r0)+2] = fmaf(v2.w, WG2((k)+3), acc[(r0)+2]); \
    acc[(r0)+3] = fmaf(v3.x, WG2(k), acc[(r0)+3]); acc[(r0)+3] = fmaf(v3.y, WG2((k)+1), acc[(r0)+3]); \
    acc[(r0)+3] = fmaf(v3.z, WG2((k)+2), acc[(r0)+3]); acc[(r0)+3] = fmaf(v3.w, WG2((k)+3), acc[(r0)+3]); }
#define GK16R(k, r0) GK4R(k, r0) GK4R((k)+4, r0) GK4R((k)+8, r0) GK4R((k)+12, r0)
#define GK64R(r0)    GK16R(0, r0) GK16R(16, r0) GK16R(32, r0) GK16R(48, r0)

#define GGRP(r0, xoff) { \
    const float* __restrict__ x0 = xb + (long)((r0)+0) * sT + (xoff); \
    const float* __restrict__ x1 = xb + (long)((r0)+1) * sT + (xoff); \
    const float* __restrict__ x2 = xb + (long)((r0)+2) * sT + (xoff); \
    const float* __restrict__ x3 = xb + (long)((r0)+3) * sT + (xoff); \
    GK64R(r0) }

template<int K>
__global__ __launch_bounds__(512) __attribute__((amdgpu_waves_per_eu(2, 2)))
void gemm_gx(const float* __restrict__ X, long sB, long sT, int toff,
             const float* __restrict__ WT, const float* __restrict__ bsum,
             float* __restrict__ gx, int Tc)
{
    const int j    = threadIdx.x;
    const int m0   = blockIdx.x * 16;
    const int b    = m0 / Tc;
    const int tcl0 = m0 % Tc;

    const float bj = bsum[j];
    vf16 acc;
#pragma unroll
    for (int r = 0; r < 16; ++r) acc[r] = bj;

    const float* __restrict__ xb = X + (long)b * sB + (long)(toff + tcl0) * sT;
    float* __restrict__ gb = gx + (long)tcl0 * (B * G4) + (long)b * G4 + j;
    const long gstride = (long)B * G4;

    {   // k-half 0: k in [0,64)
        vf32 wa, wb;
        volatile const float* wp0 = WT + j;   // volatile: pin in VGPRs
        CLDW64
        GGRP(0, 0) GGRP(4, 0) GGRP(8, 0) GGRP(12, 0)
    }
    if constexpr (K == 128) {  // k-half 1: k in [64,128)
        vf32 wa, wb;
        volatile const float* wp0 = WT + (long)64 * G4 + j;
        CLDW64
        GGRP(0, 64) GGRP(4, 64) GGRP(8, 64) GGRP(12, 64)
    }

#pragma unroll
    for (int r = 0; r < 16; ++r) gb[(long)r * gstride] = acc[r];
}

// ----------------------------------------------------------------------------
// LSTM scan. One block per batch element (grid=256 = 1 block/CU), 512
// threads. Thread tid owns gate row tid: full 128-wide dot, weights loaded
// VOLATILE so they cannot be re-materialized from memory inside the loop
// (R4-R6: backend re-issued the loads -> ~3600 cyc/step L2-bound).
// waves_per_eu(2,2): 8 waves/CU -> 256-VGPR budget, ~160 live fits.
// h broadcast via readlane; 4 accumulators; 2 barriers/step.
// ----------------------------------------------------------------------------
#define DOT1(q, ga, gb_) { float a0_ = RL(h0, q); float a1_ = RL(h1, q); \
                           ga  = fmaf(a0_, WG(q),      ga); \
                           gb_ = fmaf(a1_, WG((q)+64), gb_); }
#define DOT2(q)  DOT1(q, g0, g1) DOT1((q)+1, g2, g3)
#define DOT8(q)  DOT2(q) DOT2((q)+2) DOT2((q)+4) DOT2((q)+6)
#define DOT32(q) DOT8(q) DOT8((q)+8) DOT8((q)+16) DOT8((q)+24)

__global__ __launch_bounds__(512) __attribute__((amdgpu_waves_per_eu(2, 2)))
void lstm_scan(const float* __restrict__ gx, const float* __restrict__ Whh,
               float* __restrict__ h_state, float* __restrict__ c_state,
               float* __restrict__ h1c,     /* null for layer 1 */
               float* __restrict__ h2last,  /* null for layer 0 */
               int Tc, int storeLast)
{
    __shared__ float h_sh[H];
    __shared__ float gates[G4];

    const int tid  = threadIdx.x;   // gate row in [0, 512)
    const int b    = blockIdx.x;
    const int lane = tid & 63;

    vf32 wa, wb, wc, wd;
    {
        volatile const float* wp = Whh + (long)tid * H;   // volatile: pin
#define WLDV4(n) { float t0_ = wp[(n)]; float t1_ = wp[(n)+1]; float t2_ = wp[(n)+2]; float t3_ = wp[(n)+3]; \
                   WS((n)+0, t0_); WS((n)+1, t1_); WS((n)+2, t2_); WS((n)+3, t3_); }
#define WLDV16(n) WLDV4(n) WLDV4((n)+4) WLDV4((n)+8) WLDV4((n)+12)
        WLDV16(0) WLDV16(16) WLDV16(32) WLDV16(48)
        WLDV16(64) WLDV16(80) WLDV16(96) WLDV16(112)
#undef WLDV4
#undef WLDV16
    }

    float c = 0.f;
    if (tid < H) { h_sh[tid] = h_state[b * H + tid]; c = c_state[b * H + tid]; }
    __syncthreads();
    float h0 = h_sh[lane];
    float h1 = h_sh[64 + lane];

    const long gstride = (long)B * G4;
    const float* __restrict__ gxp = gx + (long)b * G4 + tid;
    float gc = gxp[0];
    float gn = (Tc > 1) ? gxp[gstride] : 0.f;

    for (int t = 0; t < Tc; ++t) {
        float gn2 = (t + 2 < Tc) ? gxp[(long)(t + 2) * gstride] : 0.f;

        float g0 = gc, g1 = 0.f, g2 = 0.f, g3 = 0.f;
        DOT32(0) DOT32(32)
        float g = (g0 + g1) + (g2 + g3);

        // rows [0,256) = i,f (sigmoid); [256,384) = g (tanh); [384,512) = o (sigmoid)
        float act = (tid < 2 * H || tid >= 3 * H) ? 1.f / (1.f + expf(-g)) : tanhf(g);
        gates[tid] = act;
        __syncthreads();

        if (tid < H) {
            float iv = gates[tid], fv = gates[H + tid], gv = gates[2 * H + tid], ov = gates[3 * H + tid];
            c = fmaf(fv, c, iv * gv);
            float hn = ov * tanhf(c);
            h_sh[tid] = hn;
            if (h1c) h1c[(long)b * Tc * H + (long)t * H + tid] = hn;
            if (storeLast && t == Tc - 1) h2last[b * H + tid] = hn;
        }
        __syncthreads();
        h0 = h_sh[lane];
        h1 = h_sh[64 + lane];
        gc = gn; gn = gn2;
    }

    if (tid < H) { h_state[b * H + tid] = h_sh[tid]; c_state[b * H + tid] = c; }
}

// ----------------------------------------------------------------------------
// Dropout: JAX threefry2x32, jax_threefry_partitionable=True (default since
// jax 0.4.36): counter (0, e), bits = y0 ^ y1, key (0, 42).
// ----------------------------------------------------------------------------
__device__ __forceinline__ uint32_t rotl32(uint32_t x, int r) { return (x << r) | (x >> (32 - r)); }

__global__ void dropout_kernel(const float* __restrict__ h2last, float* __restrict__ h2drop)
{
    int e = blockIdx.x * blockDim.x + threadIdx.x;
    if (e >= B * H) return;
    const uint32_t k0 = 0u, k1 = 42u, k2 = 0u ^ 42u ^ 0x1BD11BDAu;
    uint32_t x0 = 0u;
    uint32_t x1 = (uint32_t)e;
    x0 += k0; x1 += k1;
#define RG(ra,rb,rc,rd,ka,kb,inc) \
    x0 += x1; x1 = rotl32(x1, ra); x1 ^= x0; \
    x0 += x1; x1 = rotl32(x1, rb); x1 ^= x0; \
    x0 += x1; x1 = rotl32(x1, rc); x1 ^= x0; \
    x0 += x1; x1 = rotl32(x1, rd); x1 ^= x0; \
    x0 += ka; x1 += kb + inc;
    RG(13,15,26, 6, k1, k2, 1u)
    RG(17,29,16,24, k2, k0, 2u)
    RG(13,15,26, 6, k0, k1, 3u)
    RG(17,29,16,24, k1, k2, 4u)
    RG(13,15,26, 6, k2, k0, 5u)
#undef RG
    uint32_t bits = x0 ^ x1;
    float u = __uint_as_float((bits >> 9) | 0x3f800000u) - 1.0f;
    float a = h2last[e];
    h2drop[e] = (u >= 0.3f) ? (a / 0.7f) : 0.0f;
}

// ----------------------------------------------------------------------------
// Head: out[b][n] = b_out[n] + sum_u h2drop[b][u] * W_out[n][u]
// ----------------------------------------------------------------------------
__global__ void out_kernel(const float* __restrict__ h2drop, const float* __restrict__ W_out,
                           const float* __restrict__ b_out, float* __restrict__ out)
{
    int i = blockIdx.x * blockDim.x + threadIdx.x;
    if (i >= B * 2) return;
    int bb = i >> 1, n = i & 1;
    float acc = b_out[n];
    const float* __restrict__ hp = h2drop + (long)bb * H;
    const float* __restrict__ wp = W_out + (long)n * H;
#pragma unroll 4
    for (int u = 0; u < H; ++u) acc = fmaf(hp[u], wp[u], acc);
    out[i] = acc;
}

// ----------------------------------------------------------------------------
extern "C" void kernel_launch(void* const* d_in, const int* in_sizes, int n_in,
                              void* d_out, int out_size, void* d_ws, size_t ws_size,
                              hipStream_t stream)
{
    const float* x     = (const float*)d_in[0];
    const float* W_ih0 = (const float*)d_in[1];
    const float* W_hh0 = (const float*)d_in[2];
    const float* b_ih0 = (const float*)d_in[3];
    const float* b_hh0 = (const float*)d_in[4];
    const float* W_ih1 = (const float*)d_in[5];
    const float* W_hh1 = (const float*)d_in[6];
    const float* b_ih1 = (const float*)d_in[7];
    const float* b_hh1 = (const float*)d_in[8];
    const float* W_out = (const float*)d_in[9];
    const float* b_out = (const float*)d_in[10];
    float* out = (float*)d_out;

    char* ws = (char*)d_ws;
    size_t off = 0;
    auto alloc = [&](size_t bytes) { void* p = ws + off; off += (bytes + 255) & ~255ull; return p; };

    float* WT0    = (float*)alloc((size_t)FIN * G4 * 4);
    float* WT1    = (float*)alloc((size_t)H * G4 * 4);
    float* bsum0  = (float*)alloc((size_t)G4 * 4);
    float* bsum1  = (float*)alloc((size_t)G4 * 4);
    float* states = (float*)alloc((size_t)4 * B * H * 4);
    float* h0s = states, *c0s = states + B * H, *h1s = states + 2 * B * H, *c1s = states + 3 * B * H;
    float* h2last = (float*)alloc((size_t)B * H * 4);
    float* h2drop = (float*)alloc((size_t)B * H * 4);

    size_t fixed = off;
    int Tc = 16;
    const int cands[7] = {1024, 512, 256, 128, 64, 32, 16};
    for (int ci = 0; ci < 7; ++ci) {
        size_t need = fixed + (size_t)cands[ci] * ((size_t)B * H * 4 + (size_t)B * G4 * 4) + 8192;
        if (need <= ws_size) { Tc = cands[ci]; break; }
    }
    float* h1c = (float*)alloc((size_t)B * Tc * H * 4);
    float* gxb = (float*)alloc((size_t)Tc * B * G4 * 4);

    fprintf(stderr, "[kernel_launch] ws_size=%zu fixed=%zu Tc=%d total_used=%zu\n",
            ws_size, fixed, Tc, off);

    prep_kernel<<<512, 256, 0, stream>>>(W_ih0, b_ih0, b_hh0, W_ih1, b_ih1, b_hh1,
                                         WT0, WT1, bsum0, bsum1, states);

    const int nch = T / Tc;
    for (int c = 0; c < nch; ++c) {
        int t0 = c * Tc;
        gemm_gx<FIN><<<(B * Tc) / 16, 512, 0, stream>>>(x, (long)T * FIN, (long)FIN, t0,
                                                        WT0, bsum0, gxb, Tc);
        lstm_scan<<<B, 512, 0, stream>>>(gxb, W_hh0, h0s, c0s, h1c, nullptr, Tc, 0);
        gemm_gx<H><<<(B * Tc) / 16, 512, 0, stream>>>(h1c, (long)Tc * H, (long)H, 0,
                                                      WT1, bsum1, gxb, Tc);
        lstm_scan<<<B, 512, 0, stream>>>(gxb, W_hh1, h1s, c1s, nullptr, h2last, Tc,
                                         (t0 + Tc == T) ? 1 : 0);
    }

    dropout_kernel<<<128, 256, 0, stream>>>(h2last, h2drop);
    out_kernel<<<2, 256, 0, stream>>>(h2drop, W_out, b_out, out);
}

// Round 8
// 4117.128 us; speedup vs baseline: 1.5907x; 1.5907x over previous
//
#include <hip/hip_runtime.h>
#include <stdint.h>
#include <cstdio>

#define B   256
#define T   1024
#define FIN 64
#define H   128
#define G4  512   // 4*H

typedef float vf32 __attribute__((ext_vector_type(32)));
typedef float vf16 __attribute__((ext_vector_type(16)));

#define RL(v, q) __int_as_float(__builtin_amdgcn_readlane(__float_as_int(v), (q)))

// 128-float register bank in four SSA vectors. Literal indices only.
#define WG(n)    ((n) < 32 ? wa[(n) & 31] : (n) < 64 ? wb[(n) & 31] : (n) < 96 ? wc[(n) & 31] : wd[(n) & 31])
#define WS(n, v) do { if ((n) < 32) wa[(n) & 31] = (v); else if ((n) < 64) wb[(n) & 31] = (v); \
                      else if ((n) < 96) wc[(n) & 31] = (v); else wd[(n) & 31] = (v); } while (0)
// 64-float bank (two vectors)
#define WG2(n)    ((n) < 32 ? wa[(n) & 31] : wb[(n) & 31])
#define WS2(n, v) do { if ((n) < 32) wa[(n) & 31] = (v); else wb[(n) & 31] = (v); } while (0)

// Inline activations: NO libm calls in the scan loop. tanhf/expf are OCML
// calls; if they reach the RA as calls, all live VGPRs (the weights!) are
// spilled around them EVERY step — the R3..R7 spill mystery.
// sigmoid(x) = rcp(1 + exp2(-x*log2e));  tanh(x) = 2*sigmoid(2x) - 1.
#define LOG2E 1.442695041f
__device__ __forceinline__ float fast_sigmoid(float x) {
    return __builtin_amdgcn_rcpf(1.f + __builtin_amdgcn_exp2f(-LOG2E * x));
}
__device__ __forceinline__ float fast_tanh(float x) {
    return fmaf(2.f, __builtin_amdgcn_rcpf(1.f + __builtin_amdgcn_exp2f(-2.f * LOG2E * x)), -1.f);
}

// ----------------------------------------------------------------------------
// prep: transpose W_ih -> WT[k][j], bias sums, zero recurrent states
// ----------------------------------------------------------------------------
__global__ void prep_kernel(const float* __restrict__ W_ih0,
                            const float* __restrict__ b_ih0, const float* __restrict__ b_hh0,
                            const float* __restrict__ W_ih1,
                            const float* __restrict__ b_ih1, const float* __restrict__ b_hh1,
                            float* __restrict__ WT0, float* __restrict__ WT1,
                            float* __restrict__ bsum0, float* __restrict__ bsum1,
                            float* __restrict__ states /* 4*B*H */)
{
    int idx = blockIdx.x * blockDim.x + threadIdx.x;
    int n   = gridDim.x * blockDim.x;
    for (int i = idx; i < H * G4; i += n) { int k = i / G4, j = i % G4; WT1[i] = W_ih1[j * H + k]; }
    for (int i = idx; i < FIN * G4; i += n) { int k = i / G4, j = i % G4; WT0[i] = W_ih0[j * FIN + k]; }
    for (int i = idx; i < G4; i += n) { bsum0[i] = b_ih0[i] + b_hh0[i]; bsum1[i] = b_ih1[i] + b_hh1[i]; }
    for (int i = idx; i < 4 * B * H; i += n) states[i] = 0.f;
}

// ----------------------------------------------------------------------------
// gx GEMM: gx[tcl][b][j] = bias[j] + sum_k X[b, toff+tcl, k] * WT[k][j]
// 512 threads = 512 columns; 16 rows per block. K in 64-wide halves; 16
// persistent accumulators. (R6 form; volatile reverted — it forced scratch.)
// ----------------------------------------------------------------------------
#define CLDW(n) WS2(n, wp0[(long)(n) * G4]);
#define CLDW4(n)  CLDW(n) CLDW((n)+1) CLDW((n)+2) CLDW((n)+3)
#define CLDW16(n) CLDW4(n) CLDW4((n)+4) CLDW4((n)+8) CLDW4((n)+12)
#define CLDW64    CLDW16(0) CLDW16(16) CLDW16(32) CLDW16(48)

#define GK4R(k, r0) { \
    float4 v0 = *(const float4*)(x0 + (k)); \
    float4 v1 = *(const float4*)(x1 + (k)); \
    float4 v2 = *(const float4*)(x2 + (k)); \
    float4 v3 = *(const float4*)(x3 + (k)); \
    acc[(r0)+0] = fmaf(v0.x, WG2(k), acc[(r0)+0]); acc[(r0)+0] = fmaf(v0.y, WG2((k)+1), acc[(r0)+0]); \
    acc[(r0)+0] = fmaf(v0.z, WG2((k)+2), acc[(r0)+0]); acc[(r0)+0] = fmaf(v0.w, WG2((k)+3), acc[(r0)+0]); \
    acc[(r0)+1] = fmaf(v1.x, WG2(k), acc[(r0)+1]); acc[(r0)+1] = fmaf(v1.y, WG2((k)+1), acc[(r0)+1]); \
    acc[(r0)+1] = fmaf(v1.z, WG2((k)+2), acc[(r0)+1]); acc[(r0)+1] = fmaf(v1.w, WG2((k)+3), acc[(r0)+1]); \
    acc[(r0)+2] = fmaf(v2.x, WG2(k), acc[(r0)+2]); acc[(r0)+2] = fmaf(v2.y, WG2((k)+1), acc[(r0)+2]); \
    acc[(r0)+2] = fmaf(v2.z, WG2((k)+2), acc[(r0)+2]); acc[(r0)+2] = fmaf(v2.w, WG2((k)+3), acc[(r0)+2]); \
    acc[(r0)+3] = fmaf(v3.x, WG2(k), acc[(r0)+3]); acc[(r0)+3] = fmaf(v3.y, WG2((k)+1), acc[(r0)+3]); \
    acc[(r0)+3] = fmaf(v3.z, WG2((k)+2), acc[(r0)+3]); acc[(r0)+3] = fmaf(v3.w, WG2((k)+3), acc[(r0)+3]); }
#define GK16R(k, r0) GK4R(k, r0) GK4R((k)+4, r0) GK4R((k)+8, r0) GK4R((k)+12, r0)
#define GK64R(r0)    GK16R(0, r0) GK16R(16, r0) GK16R(32, r0) GK16R(48, r0)

#define GGRP(r0, xoff) { \
    const float* __restrict__ x0 = xb + (long)((r0)+0) * sT + (xoff); \
    const float* __restrict__ x1 = xb + (long)((r0)+1) * sT + (xoff); \
    const float* __restrict__ x2 = xb + (long)((r0)+2) * sT + (xoff); \
    const float* __restrict__ x3 = xb + (long)((r0)+3) * sT + (xoff); \
    GK64R(r0) }

template<int K>
__global__ __launch_bounds__(512) __attribute__((amdgpu_waves_per_eu(2, 2)))
void gemm_gx(const float* __restrict__ X, long sB, long sT, int toff,
             const float* __restrict__ WT, const float* __restrict__ bsum,
             float* __restrict__ gx, int Tc)
{
    const int j    = threadIdx.x;
    const int m0   = blockIdx.x * 16;
    const int b    = m0 / Tc;
    const int tcl0 = m0 % Tc;

    const float bj = bsum[j];
    vf16 acc;
#pragma unroll
    for (int r = 0; r < 16; ++r) acc[r] = bj;

    const float* __restrict__ xb = X + (long)b * sB + (long)(toff + tcl0) * sT;
    float* __restrict__ gb = gx + (long)tcl0 * (B * G4) + (long)b * G4 + j;
    const long gstride = (long)B * G4;

    {   // k-half 0: k in [0,64)
        vf32 wa, wb;
        const float* __restrict__ wp0 = WT + j;
        CLDW64
        GGRP(0, 0) GGRP(4, 0) GGRP(8, 0) GGRP(12, 0)
    }
    if constexpr (K == 128) {  // k-half 1: k in [64,128)
        vf32 wa, wb;
        const float* __restrict__ wp0 = WT + (long)64 * G4 + j;
        CLDW64
        GGRP(0, 64) GGRP(4, 64) GGRP(8, 64) GGRP(12, 64)
    }

#pragma unroll
    for (int r = 0; r < 16; ++r) gb[(long)r * gstride] = acc[r];
}

// ----------------------------------------------------------------------------
// LSTM scan. One block per batch element (grid=256 = 1 block/CU), 512
// threads. Thread tid owns gate row tid (full 128-wide dot, weights in SSA
// vectors). Activations fully inline (no calls!). 2 barriers/step.
// ----------------------------------------------------------------------------
#define DOT1(q, ga, gb_) { float a0_ = RL(h0, q); float a1_ = RL(h1, q); \
                           ga  = fmaf(a0_, WG(q),      ga); \
                           gb_ = fmaf(a1_, WG((q)+64), gb_); }
#define DOT2(q)  DOT1(q, g0, g1) DOT1((q)+1, g2, g3)
#define DOT8(q)  DOT2(q) DOT2((q)+2) DOT2((q)+4) DOT2((q)+6)
#define DOT32(q) DOT8(q) DOT8((q)+8) DOT8((q)+16) DOT8((q)+24)

__global__ __launch_bounds__(512) __attribute__((amdgpu_waves_per_eu(2, 2)))
void lstm_scan(const float* __restrict__ gx, const float* __restrict__ Whh,
               float* __restrict__ h_state, float* __restrict__ c_state,
               float* __restrict__ h1c,     /* null for layer 1 */
               float* __restrict__ h2last,  /* null for layer 0 */
               int Tc, int storeLast)
{
    __shared__ float h_sh[H];
    __shared__ float gates[G4];

    const int tid  = threadIdx.x;   // gate row in [0, 512)
    const int b    = blockIdx.x;
    const int lane = tid & 63;

    vf32 wa, wb, wc, wd;
    {
        const float* __restrict__ wp = Whh + (long)tid * H;
#define WLD4(n)  { float4 t4 = *(const float4*)(wp + (n)); \
                   WS((n)+0, t4.x); WS((n)+1, t4.y); WS((n)+2, t4.z); WS((n)+3, t4.w); }
#define WLD16(n) WLD4(n) WLD4((n)+4) WLD4((n)+8) WLD4((n)+12)
        WLD16(0) WLD16(16) WLD16(32) WLD16(48)
        WLD16(64) WLD16(80) WLD16(96) WLD16(112)
#undef WLD4
#undef WLD16
    }

    // Branchless activation selection: rows [0,256)+[384,512) sigmoid,
    // rows [256,384) tanh = 2*sigmoid(2x)-1.
    const bool istanh = (tid >= 2 * H && tid < 3 * H);
    const float kk = istanh ? (-2.f * LOG2E) : (-LOG2E);
    const float aa = istanh ? 2.f : 1.f;
    const float bb = istanh ? -1.f : 0.f;

    float c = 0.f;
    if (tid < H) { h_sh[tid] = h_state[b * H + tid]; c = c_state[b * H + tid]; }
    __syncthreads();
    float h0 = h_sh[lane];
    float h1 = h_sh[64 + lane];

    const long gstride = (long)B * G4;
    const float* __restrict__ gxp = gx + (long)b * G4 + tid;
    float gc = gxp[0];
    float gn = (Tc > 1) ? gxp[gstride] : 0.f;

    for (int t = 0; t < Tc; ++t) {
        float gn2 = (t + 2 < Tc) ? gxp[(long)(t + 2) * gstride] : 0.f;

        float g0 = gc, g1 = 0.f, g2 = 0.f, g3 = 0.f;
        DOT32(0) DOT32(32)
        float g = (g0 + g1) + (g2 + g3);

        float e = __builtin_amdgcn_exp2f(kk * g);
        float s = __builtin_amdgcn_rcpf(1.f + e);
        gates[tid] = fmaf(aa, s, bb);
        __syncthreads();

        if (tid < H) {
            float iv = gates[tid], fv = gates[H + tid], gv = gates[2 * H + tid], ov = gates[3 * H + tid];
            c = fmaf(fv, c, iv * gv);
            float hn = ov * fast_tanh(c);
            h_sh[tid] = hn;
            if (h1c) h1c[(long)b * Tc * H + (long)t * H + tid] = hn;
            if (storeLast && t == Tc - 1) h2last[b * H + tid] = hn;
        }
        __syncthreads();
        h0 = h_sh[lane];
        h1 = h_sh[64 + lane];
        gc = gn; gn = gn2;
    }

    if (tid < H) { h_state[b * H + tid] = h_sh[tid]; c_state[b * H + tid] = c; }
}

// ----------------------------------------------------------------------------
// Dropout: JAX threefry2x32, jax_threefry_partitionable=True (default since
// jax 0.4.36): counter (0, e), bits = y0 ^ y1, key (0, 42).
// ----------------------------------------------------------------------------
__device__ __forceinline__ uint32_t rotl32(uint32_t x, int r) { return (x << r) | (x >> (32 - r)); }

__global__ void dropout_kernel(const float* __restrict__ h2last, float* __restrict__ h2drop)
{
    int e = blockIdx.x * blockDim.x + threadIdx.x;
    if (e >= B * H) return;
    const uint32_t k0 = 0u, k1 = 42u, k2 = 0u ^ 42u ^ 0x1BD11BDAu;
    uint32_t x0 = 0u;
    uint32_t x1 = (uint32_t)e;
    x0 += k0; x1 += k1;
#define RG(ra,rb,rc,rd,ka,kb,inc) \
    x0 += x1; x1 = rotl32(x1, ra); x1 ^= x0; \
    x0 += x1; x1 = rotl32(x1, rb); x1 ^= x0; \
    x0 += x1; x1 = rotl32(x1, rc); x1 ^= x0; \
    x0 += x1; x1 = rotl32(x1, rd); x1 ^= x0; \
    x0 += ka; x1 += kb + inc;
    RG(13,15,26, 6, k1, k2, 1u)
    RG(17,29,16,24, k2, k0, 2u)
    RG(13,15,26, 6, k0, k1, 3u)
    RG(17,29,16,24, k1, k2, 4u)
    RG(13,15,26, 6, k2, k0, 5u)
#undef RG
    uint32_t bits = x0 ^ x1;
    float u = __uint_as_float((bits >> 9) | 0x3f800000u) - 1.0f;
    float a = h2last[e];
    h2drop[e] = (u >= 0.3f) ? (a / 0.7f) : 0.0f;
}

// ----------------------------------------------------------------------------
// Head: out[b][n] = b_out[n] + sum_u h2drop[b][u] * W_out[n][u]
// ----------------------------------------------------------------------------
__global__ void out_kernel(const float* __restrict__ h2drop, const float* __restrict__ W_out,
                           const float* __restrict__ b_out, float* __restrict__ out)
{
    int i = blockIdx.x * blockDim.x + threadIdx.x;
    if (i >= B * 2) return;
    int bb = i >> 1, n = i & 1;
    float acc = b_out[n];
    const float* __restrict__ hp = h2drop + (long)bb * H;
    const float* __restrict__ wp = W_out + (long)n * H;
#pragma unroll 4
    for (int u = 0; u < H; ++u) acc = fmaf(hp[u], wp[u], acc);
    out[i] = acc;
}

// ----------------------------------------------------------------------------
extern "C" void kernel_launch(void* const* d_in, const int* in_sizes, int n_in,
                              void* d_out, int out_size, void* d_ws, size_t ws_size,
                              hipStream_t stream)
{
    const float* x     = (const float*)d_in[0];
    const float* W_ih0 = (const float*)d_in[1];
    const float* W_hh0 = (const float*)d_in[2];
    const float* b_ih0 = (const float*)d_in[3];
    const float* b_hh0 = (const float*)d_in[4];
    const float* W_ih1 = (const float*)d_in[5];
    const float* W_hh1 = (const float*)d_in[6];
    const float* b_ih1 = (const float*)d_in[7];
    const float* b_hh1 = (const float*)d_in[8];
    const float* W_out = (const float*)d_in[9];
    const float* b_out = (const float*)d_in[10];
    float* out = (float*)d_out;

    char* ws = (char*)d_ws;
    size_t off = 0;
    auto alloc = [&](size_t bytes) { void* p = ws + off; off += (bytes + 255) & ~255ull; return p; };

    float* WT0    = (float*)alloc((size_t)FIN * G4 * 4);
    float* WT1    = (float*)alloc((size_t)H * G4 * 4);
    float* bsum0  = (float*)alloc((size_t)G4 * 4);
    float* bsum1  = (float*)alloc((size_t)G4 * 4);
    float* states = (float*)alloc((size_t)4 * B * H * 4);
    float* h0s = states, *c0s = states + B * H, *h1s = states + 2 * B * H, *c1s = states + 3 * B * H;
    float* h2last = (float*)alloc((size_t)B * H * 4);
    float* h2drop = (float*)alloc((size_t)B * H * 4);

    size_t fixed = off;
    int Tc = 16;
    const int cands[7] = {1024, 512, 256, 128, 64, 32, 16};
    for (int ci = 0; ci < 7; ++ci) {
        size_t need = fixed + (size_t)cands[ci] * ((size_t)B * H * 4 + (size_t)B * G4 * 4) + 8192;
        if (need <= ws_size) { Tc = cands[ci]; break; }
    }
    float* h1c = (float*)alloc((size_t)B * Tc * H * 4);
    float* gxb = (float*)alloc((size_t)Tc * B * G4 * 4);

    fprintf(stderr, "[kernel_launch] ws_size=%zu fixed=%zu Tc=%d total_used=%zu\n",
            ws_size, fixed, Tc, off);

    prep_kernel<<<512, 256, 0, stream>>>(W_ih0, b_ih0, b_hh0, W_ih1, b_ih1, b_hh1,
                                         WT0, WT1, bsum0, bsum1, states);

    const int nch = T / Tc;
    for (int c = 0; c < nch; ++c) {
        int t0 = c * Tc;
        gemm_gx<FIN><<<(B * Tc) / 16, 512, 0, stream>>>(x, (long)T * FIN, (long)FIN, t0,
                                                        WT0, bsum0, gxb, Tc);
        lstm_scan<<<B, 512, 0, stream>>>(gxb, W_hh0, h0s, c0s, h1c, nullptr, Tc, 0);
        gemm_gx<H><<<(B * Tc) / 16, 512, 0, stream>>>(h1c, (long)Tc * H, (long)H, 0,
                                                      WT1, bsum1, gxb, Tc);
        lstm_scan<<<B, 512, 0, stream>>>(gxb, W_hh1, h1s, c1s, nullptr, h2last, Tc,
                                         (t0 + Tc == T) ? 1 : 0);
    }

    dropout_kernel<<<128, 256, 0, stream>>>(h2last, h2drop);
    out_kernel<<<2, 256, 0, stream>>>(h2drop, W_out, b_out, out);
}

// Round 9
// 3576.572 us; speedup vs baseline: 1.8312x; 1.1511x over previous
//
#include <hip/hip_runtime.h>
#include <stdint.h>
#include <cstdio>

#define B   256
#define T   1024
#define FIN 64
#define H   128
#define G4  512   // 4*H

typedef float vf16 __attribute__((ext_vector_type(16)));

#define RL(v, q) __int_as_float(__builtin_amdgcn_readlane(__float_as_int(v), (q)))

// 128-float register bank in eight 16-wide SSA vectors (16-reg VGPR tuples,
// same shape as MFMA accumulators). Literal indices only.
#define WG(n)    ((n) < 16 ? w0[(n) & 15] : (n) < 32 ? w1[(n) & 15] : (n) < 48 ? w2[(n) & 15] : \
                  (n) < 64 ? w3[(n) & 15] : (n) < 80 ? w4[(n) & 15] : (n) < 96 ? w5[(n) & 15] : \
                  (n) < 112 ? w6[(n) & 15] : w7[(n) & 15])
#define WS(n, v) do { if ((n) < 16) w0[(n) & 15] = (v); else if ((n) < 32) w1[(n) & 15] = (v); \
                      else if ((n) < 48) w2[(n) & 15] = (v); else if ((n) < 64) w3[(n) & 15] = (v); \
                      else if ((n) < 80) w4[(n) & 15] = (v); else if ((n) < 96) w5[(n) & 15] = (v); \
                      else if ((n) < 112) w6[(n) & 15] = (v); else w7[(n) & 15] = (v); } while (0)

// Inline activations (no OCML calls in the loop — R8: removing calls cut
// 382->303 us). sigmoid(x)=rcp(1+exp2(-x*log2e)); tanh(x)=2*sigmoid(2x)-1.
#define LOG2E 1.442695041f
__device__ __forceinline__ float fast_tanh(float x) {
    return fmaf(2.f, __builtin_amdgcn_rcpf(1.f + __builtin_amdgcn_exp2f(-2.f * LOG2E * x)), -1.f);
}

// ----------------------------------------------------------------------------
// prep: transpose W_ih -> WT[k][j], bias sums, zero recurrent states
// ----------------------------------------------------------------------------
__global__ void prep_kernel(const float* __restrict__ W_ih0,
                            const float* __restrict__ b_ih0, const float* __restrict__ b_hh0,
                            const float* __restrict__ W_ih1,
                            const float* __restrict__ b_ih1, const float* __restrict__ b_hh1,
                            float* __restrict__ WT0, float* __restrict__ WT1,
                            float* __restrict__ bsum0, float* __restrict__ bsum1,
                            float* __restrict__ states /* 4*B*H */)
{
    int idx = blockIdx.x * blockDim.x + threadIdx.x;
    int n   = gridDim.x * blockDim.x;
    for (int i = idx; i < H * G4; i += n) { int k = i / G4, j = i % G4; WT1[i] = W_ih1[j * H + k]; }
    for (int i = idx; i < FIN * G4; i += n) { int k = i / G4, j = i % G4; WT0[i] = W_ih0[j * FIN + k]; }
    for (int i = idx; i < G4; i += n) { bsum0[i] = b_ih0[i] + b_hh0[i]; bsum1[i] = b_ih1[i] + b_hh1[i]; }
    for (int i = idx; i < 4 * B * H; i += n) states[i] = 0.f;
}

// ----------------------------------------------------------------------------
// gx GEMM: gx[tcl][b][j] = bias[j] + sum_k X[b, toff+tcl, k] * WT[k][j]
// 512 threads = 512 columns; 16 rows per block. K in 32-wide chunks (only 32
// weights live -> small footprint) + waves_per_eu(4) for 4 waves/SIMD of
// VMEM latency hiding (R8: 2 waves/SIMD left gemm 4x over issue model).
// ----------------------------------------------------------------------------
#define GW(n)    ((n) < 16 ? u0[(n) & 15] : u1[(n) & 15])
#define GWS(n,v) do { if ((n) < 16) u0[(n) & 15] = (v); else u1[(n) & 15] = (v); } while (0)

#define GLD4(n) GWS((n), wp0[(long)(n) * G4]); GWS((n)+1, wp0[(long)((n)+1) * G4]); \
                GWS((n)+2, wp0[(long)((n)+2) * G4]); GWS((n)+3, wp0[(long)((n)+3) * G4]);

#define GMAC4(kk, r0) { \
    float4 v0 = *(const float4*)(x0 + (kk)); \
    float4 v1 = *(const float4*)(x1 + (kk)); \
    float4 v2 = *(const float4*)(x2 + (kk)); \
    float4 v3 = *(const float4*)(x3 + (kk)); \
    acc[(r0)+0] = fmaf(v0.x, GW(kk), acc[(r0)+0]); acc[(r0)+0] = fmaf(v0.y, GW((kk)+1), acc[(r0)+0]); \
    acc[(r0)+0] = fmaf(v0.z, GW((kk)+2), acc[(r0)+0]); acc[(r0)+0] = fmaf(v0.w, GW((kk)+3), acc[(r0)+0]); \
    acc[(r0)+1] = fmaf(v1.x, GW(kk), acc[(r0)+1]); acc[(r0)+1] = fmaf(v1.y, GW((kk)+1), acc[(r0)+1]); \
    acc[(r0)+1] = fmaf(v1.z, GW((kk)+2), acc[(r0)+1]); acc[(r0)+1] = fmaf(v1.w, GW((kk)+3), acc[(r0)+1]); \
    acc[(r0)+2] = fmaf(v2.x, GW(kk), acc[(r0)+2]); acc[(r0)+2] = fmaf(v2.y, GW((kk)+1), acc[(r0)+2]); \
    acc[(r0)+2] = fmaf(v2.z, GW((kk)+2), acc[(r0)+2]); acc[(r0)+2] = fmaf(v2.w, GW((kk)+3), acc[(r0)+2]); \
    acc[(r0)+3] = fmaf(v3.x, GW(kk), acc[(r0)+3]); acc[(r0)+3] = fmaf(v3.y, GW((kk)+1), acc[(r0)+3]); \
    acc[(r0)+3] = fmaf(v3.z, GW((kk)+2), acc[(r0)+3]); acc[(r0)+3] = fmaf(v3.w, GW((kk)+3), acc[(r0)+3]); }

#define GROW4(r0, kb) { \
    const float* __restrict__ x0 = xb + (long)((r0)+0) * sT + (kb); \
    const float* __restrict__ x1 = xb + (long)((r0)+1) * sT + (kb); \
    const float* __restrict__ x2 = xb + (long)((r0)+2) * sT + (kb); \
    const float* __restrict__ x3 = xb + (long)((r0)+3) * sT + (kb); \
    GMAC4(0,r0) GMAC4(4,r0) GMAC4(8,r0) GMAC4(12,r0) \
    GMAC4(16,r0) GMAC4(20,r0) GMAC4(24,r0) GMAC4(28,r0) }

#define GCHUNK(kb) { \
    vf16 u0, u1; \
    const float* __restrict__ wp0 = WT + (long)(kb) * G4 + j; \
    GLD4(0) GLD4(4) GLD4(8) GLD4(12) GLD4(16) GLD4(20) GLD4(24) GLD4(28) \
    GROW4(0,kb) GROW4(4,kb) GROW4(8,kb) GROW4(12,kb) }

template<int K>
__global__ __launch_bounds__(512) __attribute__((amdgpu_waves_per_eu(4)))
void gemm_gx(const float* __restrict__ X, long sB, long sT, int toff,
             const float* __restrict__ WT, const float* __restrict__ bsum,
             float* __restrict__ gx, int Tc)
{
    const int j    = threadIdx.x;
    const int m0   = blockIdx.x * 16;
    const int b    = m0 / Tc;
    const int tcl0 = m0 % Tc;

    const float bj = bsum[j];
    vf16 acc;
#pragma unroll
    for (int r = 0; r < 16; ++r) acc[r] = bj;

    const float* __restrict__ xb = X + (long)b * sB + (long)(toff + tcl0) * sT;
    float* __restrict__ gb = gx + (long)tcl0 * (B * G4) + (long)b * G4 + j;
    const long gstride = (long)B * G4;

    GCHUNK(0) GCHUNK(32)
    if constexpr (K == 128) { GCHUNK(64) GCHUNK(96) }

#pragma unroll
    for (int r = 0; r < 16; ++r) gb[(long)r * gstride] = acc[r];
}

// ----------------------------------------------------------------------------
// LSTM scan. One block per batch element (grid=256 = 1 block/CU), 512
// threads. Thread tid owns gate row tid (full 128-wide dot). The empty asm
// with "+v" on all eight weight vectors INSIDE the loop makes the weights a
// loop-carried VGPR chain: the scheduler cannot sink the loads into the loop
// (R8 diag: it re-fetched 512 B/thread/step from L1/L2, ~2840 cyc/step) and
// the RA cannot spill/remat them. waves_per_eu(2): 256-VGPR budget.
// ----------------------------------------------------------------------------
#define DOT1(q, ga, gb_) { float a0_ = RL(h0, q); float a1_ = RL(h1, q); \
                           ga  = fmaf(a0_, WG(q),      ga); \
                           gb_ = fmaf(a1_, WG((q)+64), gb_); }
#define DOT2(q)  DOT1(q, g0, g1) DOT1((q)+1, g2, g3)
#define DOT8(q)  DOT2(q) DOT2((q)+2) DOT2((q)+4) DOT2((q)+6)
#define DOT32(q) DOT8(q) DOT8((q)+8) DOT8((q)+16) DOT8((q)+24)

__global__ __launch_bounds__(512) __attribute__((amdgpu_waves_per_eu(2)))
void lstm_scan(const float* __restrict__ gx, const float* __restrict__ Whh,
               float* __restrict__ h_state, float* __restrict__ c_state,
               float* __restrict__ h1c,     /* null for layer 1 */
               float* __restrict__ h2last,  /* null for layer 0 */
               int Tc, int storeLast)
{
    __shared__ float h_sh[H];
    __shared__ float gates[G4];

    const int tid  = threadIdx.x;   // gate row in [0, 512)
    const int b    = blockIdx.x;
    const int lane = tid & 63;

    vf16 w0, w1, w2, w3, w4, w5, w6, w7;
    {
        const float* __restrict__ wp = Whh + (long)tid * H;
#define WLD4(n)  { float4 t4 = *(const float4*)(wp + (n)); \
                   WS((n)+0, t4.x); WS((n)+1, t4.y); WS((n)+2, t4.z); WS((n)+3, t4.w); }
#define WLD16(n) WLD4(n) WLD4((n)+4) WLD4((n)+8) WLD4((n)+12)
        WLD16(0) WLD16(16) WLD16(32) WLD16(48)
        WLD16(64) WLD16(80) WLD16(96) WLD16(112)
#undef WLD4
#undef WLD16
    }

    // Branchless activation constants: rows [0,256)+[384,512) sigmoid,
    // rows [256,384) tanh = 2*sigmoid(2x)-1.
    const bool istanh = (tid >= 2 * H && tid < 3 * H);
    const float kk = istanh ? (-2.f * LOG2E) : (-LOG2E);
    const float aa = istanh ? 2.f : 1.f;
    const float bb = istanh ? -1.f : 0.f;

    float c = 0.f;
    if (tid < H) { h_sh[tid] = h_state[b * H + tid]; c = c_state[b * H + tid]; }
    __syncthreads();
    float h0 = h_sh[lane];
    float h1 = h_sh[64 + lane];

    const long gstride = (long)B * G4;
    const float* __restrict__ gxp = gx + (long)b * G4 + tid;
    float gc = gxp[0];
    float gn = (Tc > 1) ? gxp[gstride] : 0.f;

    for (int t = 0; t < Tc; ++t) {
        // Pin the weight bank: loop-carried through an opaque asm -> loads
        // stay in the preheader, values stay in VGPRs.
        asm("" : "+v"(w0), "+v"(w1), "+v"(w2), "+v"(w3),
                 "+v"(w4), "+v"(w5), "+v"(w6), "+v"(w7));

        float gn2 = (t + 2 < Tc) ? gxp[(long)(t + 2) * gstride] : 0.f;

        float g0 = gc, g1 = 0.f, g2 = 0.f, g3 = 0.f;
        DOT32(0) DOT32(32)
        float g = (g0 + g1) + (g2 + g3);

        float e = __builtin_amdgcn_exp2f(kk * g);
        float s = __builtin_amdgcn_rcpf(1.f + e);
        gates[tid] = fmaf(aa, s, bb);
        __syncthreads();

        if (tid < H) {
            float iv = gates[tid], fv = gates[H + tid], gv = gates[2 * H + tid], ov = gates[3 * H + tid];
            c = fmaf(fv, c, iv * gv);
            float hn = ov * fast_tanh(c);
            h_sh[tid] = hn;
            if (h1c) h1c[(long)b * Tc * H + (long)t * H + tid] = hn;
            if (storeLast && t == Tc - 1) h2last[b * H + tid] = hn;
        }
        __syncthreads();
        h0 = h_sh[lane];
        h1 = h_sh[64 + lane];
        gc = gn; gn = gn2;
    }

    if (tid < H) { h_state[b * H + tid] = h_sh[tid]; c_state[b * H + tid] = c; }
}

// ----------------------------------------------------------------------------
// Dropout: JAX threefry2x32, jax_threefry_partitionable=True (default since
// jax 0.4.36): counter (0, e), bits = y0 ^ y1, key (0, 42).
// ----------------------------------------------------------------------------
__device__ __forceinline__ uint32_t rotl32(uint32_t x, int r) { return (x << r) | (x >> (32 - r)); }

__global__ void dropout_kernel(const float* __restrict__ h2last, float* __restrict__ h2drop)
{
    int e = blockIdx.x * blockDim.x + threadIdx.x;
    if (e >= B * H) return;
    const uint32_t k0 = 0u, k1 = 42u, k2 = 0u ^ 42u ^ 0x1BD11BDAu;
    uint32_t x0 = 0u;
    uint32_t x1 = (uint32_t)e;
    x0 += k0; x1 += k1;
#define RG(ra,rb,rc,rd,ka,kb,inc) \
    x0 += x1; x1 = rotl32(x1, ra); x1 ^= x0; \
    x0 += x1; x1 = rotl32(x1, rb); x1 ^= x0; \
    x0 += x1; x1 = rotl32(x1, rc); x1 ^= x0; \
    x0 += x1; x1 = rotl32(x1, rd); x1 ^= x0; \
    x0 += ka; x1 += kb + inc;
    RG(13,15,26, 6, k1, k2, 1u)
    RG(17,29,16,24, k2, k0, 2u)
    RG(13,15,26, 6, k0, k1, 3u)
    RG(17,29,16,24, k1, k2, 4u)
    RG(13,15,26, 6, k2, k0, 5u)
#undef RG
    uint32_t bits = x0 ^ x1;
    float u = __uint_as_float((bits >> 9) | 0x3f800000u) - 1.0f;
    float a = h2last[e];
    h2drop[e] = (u >= 0.3f) ? (a / 0.7f) : 0.0f;
}

// ----------------------------------------------------------------------------
// Head: out[b][n] = b_out[n] + sum_u h2drop[b][u] * W_out[n][u]
// ----------------------------------------------------------------------------
__global__ void out_kernel(const float* __restrict__ h2drop, const float* __restrict__ W_out,
                           const float* __restrict__ b_out, float* __restrict__ out)
{
    int i = blockIdx.x * blockDim.x + threadIdx.x;
    if (i >= B * 2) return;
    int bb = i >> 1, n = i & 1;
    float acc = b_out[n];
    const float* __restrict__ hp = h2drop + (long)bb * H;
    const float* __restrict__ wp = W_out + (long)n * H;
#pragma unroll 4
    for (int u = 0; u < H; ++u) acc = fmaf(hp[u], wp[u], acc);
    out[i] = acc;
}

// ----------------------------------------------------------------------------
extern "C" void kernel_launch(void* const* d_in, const int* in_sizes, int n_in,
                              void* d_out, int out_size, void* d_ws, size_t ws_size,
                              hipStream_t stream)
{
    const float* x     = (const float*)d_in[0];
    const float* W_ih0 = (const float*)d_in[1];
    const float* W_hh0 = (const float*)d_in[2];
    const float* b_ih0 = (const float*)d_in[3];
    const float* b_hh0 = (const float*)d_in[4];
    const float* W_ih1 = (const float*)d_in[5];
    const float* W_hh1 = (const float*)d_in[6];
    const float* b_ih1 = (const float*)d_in[7];
    const float* b_hh1 = (const float*)d_in[8];
    const float* W_out = (const float*)d_in[9];
    const float* b_out = (const float*)d_in[10];
    float* out = (float*)d_out;

    char* ws = (char*)d_ws;
    size_t off = 0;
    auto alloc = [&](size_t bytes) { void* p = ws + off; off += (bytes + 255) & ~255ull; return p; };

    float* WT0    = (float*)alloc((size_t)FIN * G4 * 4);
    float* WT1    = (float*)alloc((size_t)H * G4 * 4);
    float* bsum0  = (float*)alloc((size_t)G4 * 4);
    float* bsum1  = (float*)alloc((size_t)G4 * 4);
    float* states = (float*)alloc((size_t)4 * B * H * 4);
    float* h0s = states, *c0s = states + B * H, *h1s = states + 2 * B * H, *c1s = states + 3 * B * H;
    float* h2last = (float*)alloc((size_t)B * H * 4);
    float* h2drop = (float*)alloc((size_t)B * H * 4);

    size_t fixed = off;
    int Tc = 16;
    const int cands[7] = {1024, 512, 256, 128, 64, 32, 16};
    for (int ci = 0; ci < 7; ++ci) {
        size_t need = fixed + (size_t)cands[ci] * ((size_t)B * H * 4 + (size_t)B * G4 * 4) + 8192;
        if (need <= ws_size) { Tc = cands[ci]; break; }
    }
    float* h1c = (float*)alloc((size_t)B * Tc * H * 4);
    float* gxb = (float*)alloc((size_t)Tc * B * G4 * 4);

    fprintf(stderr, "[kernel_launch] ws_size=%zu fixed=%zu Tc=%d total_used=%zu\n",
            ws_size, fixed, Tc, off);

    prep_kernel<<<512, 256, 0, stream>>>(W_ih0, b_ih0, b_hh0, W_ih1, b_ih1, b_hh1,
                                         WT0, WT1, bsum0, bsum1, states);

    const int nch = T / Tc;
    for (int c = 0; c < nch; ++c) {
        int t0 = c * Tc;
        gemm_gx<FIN><<<(B * Tc) / 16, 512, 0, stream>>>(x, (long)T * FIN, (long)FIN, t0,
                                                        WT0, bsum0, gxb, Tc);
        lstm_scan<<<B, 512, 0, stream>>>(gxb, W_hh0, h0s, c0s, h1c, nullptr, Tc, 0);
        gemm_gx<H><<<(B * Tc) / 16, 512, 0, stream>>>(h1c, (long)Tc * H, (long)H, 0,
                                                      WT1, bsum1, gxb, Tc);
        lstm_scan<<<B, 512, 0, stream>>>(gxb, W_hh1, h1s, c1s, nullptr, h2last, Tc,
                                         (t0 + Tc == T) ? 1 : 0);
    }

    dropout_kernel<<<128, 256, 0, stream>>>(h2last, h2drop);
    out_kernel<<<2, 256, 0, stream>>>(h2drop, W_out, b_out, out);
}

// Round 10
// 3499.557 us; speedup vs baseline: 1.8715x; 1.0220x over previous
//
#include <hip/hip_runtime.h>
#include <stdint.h>
#include <cstdio>

#define B   256
#define T   1024
#define FIN 64
#define H   128
#define G4  512   // 4*H

typedef float vf16 __attribute__((ext_vector_type(16)));

// Inline activations (no OCML calls — R8: calls forced spills around them).
#define LOG2E 1.442695041f
__device__ __forceinline__ float fast_tanh(float x) {
    return fmaf(2.f, __builtin_amdgcn_rcpf(1.f + __builtin_amdgcn_exp2f(-2.f * LOG2E * x)), -1.f);
}

// ----------------------------------------------------------------------------
// prep: transpose W_ih -> WT[k][j], bias sums, zero recurrent states
// ----------------------------------------------------------------------------
__global__ void prep_kernel(const float* __restrict__ W_ih0,
                            const float* __restrict__ b_ih0, const float* __restrict__ b_hh0,
                            const float* __restrict__ W_ih1,
                            const float* __restrict__ b_ih1, const float* __restrict__ b_hh1,
                            float* __restrict__ WT0, float* __restrict__ WT1,
                            float* __restrict__ bsum0, float* __restrict__ bsum1,
                            float* __restrict__ states /* 4*B*H */)
{
    int idx = blockIdx.x * blockDim.x + threadIdx.x;
    int n   = gridDim.x * blockDim.x;
    for (int i = idx; i < H * G4; i += n) { int k = i / G4, j = i % G4; WT1[i] = W_ih1[j * H + k]; }
    for (int i = idx; i < FIN * G4; i += n) { int k = i / G4, j = i % G4; WT0[i] = W_ih0[j * FIN + k]; }
    for (int i = idx; i < G4; i += n) { bsum0[i] = b_ih0[i] + b_hh0[i]; bsum1[i] = b_ih1[i] + b_hh1[i]; }
    for (int i = idx; i < 4 * B * H; i += n) states[i] = 0.f;
}

// ----------------------------------------------------------------------------
// gx GEMM (unchanged from R9 — it improved): 512 threads = 512 columns; 16
// rows per block; K in 32-wide chunks; waves_per_eu(4).
// ----------------------------------------------------------------------------
#define GW(n)    ((n) < 16 ? u0[(n) & 15] : u1[(n) & 15])
#define GWS(n,v) do { if ((n) < 16) u0[(n) & 15] = (v); else u1[(n) & 15] = (v); } while (0)

#define GLD4(n) GWS((n), wp0[(long)(n) * G4]); GWS((n)+1, wp0[(long)((n)+1) * G4]); \
                GWS((n)+2, wp0[(long)((n)+2) * G4]); GWS((n)+3, wp0[(long)((n)+3) * G4]);

#define GMAC4(kk, r0) { \
    float4 v0 = *(const float4*)(x0 + (kk)); \
    float4 v1 = *(const float4*)(x1 + (kk)); \
    float4 v2 = *(const float4*)(x2 + (kk)); \
    float4 v3 = *(const float4*)(x3 + (kk)); \
    acc[(r0)+0] = fmaf(v0.x, GW(kk), acc[(r0)+0]); acc[(r0)+0] = fmaf(v0.y, GW((kk)+1), acc[(r0)+0]); \
    acc[(r0)+0] = fmaf(v0.z, GW((kk)+2), acc[(r0)+0]); acc[(r0)+0] = fmaf(v0.w, GW((kk)+3), acc[(r0)+0]); \
    acc[(r0)+1] = fmaf(v1.x, GW(kk), acc[(r0)+1]); acc[(r0)+1] = fmaf(v1.y, GW((kk)+1), acc[(r0)+1]); \
    acc[(r0)+1] = fmaf(v1.z, GW((kk)+2), acc[(r0)+1]); acc[(r0)+1] = fmaf(v1.w, GW((kk)+3), acc[(r0)+1]); \
    acc[(r0)+2] = fmaf(v2.x, GW(kk), acc[(r0)+2]); acc[(r0)+2] = fmaf(v2.y, GW((kk)+1), acc[(r0)+2]); \
    acc[(r0)+2] = fmaf(v2.z, GW((kk)+2), acc[(r0)+2]); acc[(r0)+2] = fmaf(v2.w, GW((kk)+3), acc[(r0)+2]); \
    acc[(r0)+3] = fmaf(v3.x, GW(kk), acc[(r0)+3]); acc[(r0)+3] = fmaf(v3.y, GW((kk)+1), acc[(r0)+3]); \
    acc[(r0)+3] = fmaf(v3.z, GW((kk)+2), acc[(r0)+3]); acc[(r0)+3] = fmaf(v3.w, GW((kk)+3), acc[(r0)+3]); }

#define GROW4(r0, kb) { \
    const float* __restrict__ x0 = xb + (long)((r0)+0) * sT + (kb); \
    const float* __restrict__ x1 = xb + (long)((r0)+1) * sT + (kb); \
    const float* __restrict__ x2 = xb + (long)((r0)+2) * sT + (kb); \
    const float* __restrict__ x3 = xb + (long)((r0)+3) * sT + (kb); \
    GMAC4(0,r0) GMAC4(4,r0) GMAC4(8,r0) GMAC4(12,r0) \
    GMAC4(16,r0) GMAC4(20,r0) GMAC4(24,r0) GMAC4(28,r0) }

#define GCHUNK(kb) { \
    vf16 u0, u1; \
    const float* __restrict__ wp0 = WT + (long)(kb) * G4 + j; \
    GLD4(0) GLD4(4) GLD4(8) GLD4(12) GLD4(16) GLD4(20) GLD4(24) GLD4(28) \
    GROW4(0,kb) GROW4(4,kb) GROW4(8,kb) GROW4(12,kb) }

template<int K>
__global__ __launch_bounds__(512) __attribute__((amdgpu_waves_per_eu(4)))
void gemm_gx(const float* __restrict__ X, long sB, long sT, int toff,
             const float* __restrict__ WT, const float* __restrict__ bsum,
             float* __restrict__ gx, int Tc)
{
    const int j    = threadIdx.x;
    const int m0   = blockIdx.x * 16;
    const int b    = m0 / Tc;
    const int tcl0 = m0 % Tc;

    const float bj = bsum[j];
    vf16 acc;
#pragma unroll
    for (int r = 0; r < 16; ++r) acc[r] = bj;

    const float* __restrict__ xb = X + (long)b * sB + (long)(toff + tcl0) * sT;
    float* __restrict__ gb = gx + (long)tcl0 * (B * G4) + (long)b * G4 + j;
    const long gstride = (long)B * G4;

    GCHUNK(0) GCHUNK(32)
    if constexpr (K == 128) { GCHUNK(64) GCHUNK(96) }

#pragma unroll
    for (int r = 0; r < 16; ++r) gb[(long)r * gstride] = acc[r];
}

// ----------------------------------------------------------------------------
// LSTM scan. One block per batch (grid=256), 512 threads; thread owns gate
// row tid. The 128-MAC dot is HAND-WRITTEN ASM with the weights as 128
// SCALAR "v" operands: (1) scalar regs have no tuple-contiguity constraint
// (R5/R6/R9 failure: vf16/vf32 operands demand aligned 16/32-reg tuples ->
// RA splits & remats); (2) weights pass through an opaque asm touch after
// load -> remat is illegal; (3) v_fmac consumes them INSIDE asm -> must be
// VGPR-resident at use. h broadcast: v_readlane -> SGPR temp -> v_fmac
// (SGPR src0 legal in VOP2; >=2-instr gap covers the VALU->SGPR hazard).
// ----------------------------------------------------------------------------
#define Q4(l0,l1,l2,l3, hn, w0,w1,w2,w3) \
  "v_readlane_b32 %[t0], %[" hn "], " #l0 "\n\t" \
  "v_readlane_b32 %[t1], %[" hn "], " #l1 "\n\t" \
  "v_readlane_b32 %[t2], %[" hn "], " #l2 "\n\t" \
  "v_readlane_b32 %[t3], %[" hn "], " #l3 "\n\t" \
  "v_fmac_f32 %[a0], %[t0], %[" w0 "]\n\t" \
  "v_fmac_f32 %[a1], %[t1], %[" w1 "]\n\t" \
  "v_fmac_f32 %[a2], %[t2], %[" w2 "]\n\t" \
  "v_fmac_f32 %[a3], %[t3], %[" w3 "]\n\t"

#define LW8(a,b,c,d,e,f,g,h) float W##a=wp[a],W##b=wp[b],W##c=wp[c],W##d=wp[d], \
                                   W##e=wp[e],W##f=wp[f],W##g=wp[g],W##h=wp[h];
#define TL8(a,b,c,d,e,f,g,h) [W##a]"+v"(W##a),[W##b]"+v"(W##b),[W##c]"+v"(W##c),[W##d]"+v"(W##d), \
                             [W##e]"+v"(W##e),[W##f]"+v"(W##f),[W##g]"+v"(W##g),[W##h]"+v"(W##h)
#define IN8(a,b,c,d,e,f,g,h) [W##a]"v"(W##a),[W##b]"v"(W##b),[W##c]"v"(W##c),[W##d]"v"(W##d), \
                             [W##e]"v"(W##e),[W##f]"v"(W##f),[W##g]"v"(W##g),[W##h]"v"(W##h)

__global__ __launch_bounds__(512) __attribute__((amdgpu_waves_per_eu(2)))
void lstm_scan(const float* __restrict__ gx, const float* __restrict__ Whh,
               float* __restrict__ h_state, float* __restrict__ c_state,
               float* __restrict__ h1c,     /* null for layer 1 */
               float* __restrict__ h2last,  /* null for layer 0 */
               int Tc, int storeLast)
{
    __shared__ float h_sh[H];
    __shared__ float gates[G4];

    const int tid  = threadIdx.x;   // gate row in [0, 512)
    const int b    = blockIdx.x;
    const int lane = tid & 63;

    const float* __restrict__ wp = Whh + (long)tid * H;
    LW8(0,1,2,3,4,5,6,7)           LW8(8,9,10,11,12,13,14,15)
    LW8(16,17,18,19,20,21,22,23)   LW8(24,25,26,27,28,29,30,31)
    LW8(32,33,34,35,36,37,38,39)   LW8(40,41,42,43,44,45,46,47)
    LW8(48,49,50,51,52,53,54,55)   LW8(56,57,58,59,60,61,62,63)
    LW8(64,65,66,67,68,69,70,71)   LW8(72,73,74,75,76,77,78,79)
    LW8(80,81,82,83,84,85,86,87)   LW8(88,89,90,91,92,93,94,95)
    LW8(96,97,98,99,100,101,102,103)    LW8(104,105,106,107,108,109,110,111)
    LW8(112,113,114,115,116,117,118,119) LW8(120,121,122,123,124,125,126,127)
    // Opaque touches: weights become asm-defined values (remat illegal).
    asm("" : TL8(0,1,2,3,4,5,6,7), TL8(8,9,10,11,12,13,14,15),
             TL8(16,17,18,19,20,21,22,23), TL8(24,25,26,27,28,29,30,31));
    asm("" : TL8(32,33,34,35,36,37,38,39), TL8(40,41,42,43,44,45,46,47),
             TL8(48,49,50,51,52,53,54,55), TL8(56,57,58,59,60,61,62,63));
    asm("" : TL8(64,65,66,67,68,69,70,71), TL8(72,73,74,75,76,77,78,79),
             TL8(80,81,82,83,84,85,86,87), TL8(88,89,90,91,92,93,94,95));
    asm("" : TL8(96,97,98,99,100,101,102,103), TL8(104,105,106,107,108,109,110,111),
             TL8(112,113,114,115,116,117,118,119), TL8(120,121,122,123,124,125,126,127));

    const bool istanh = (tid >= 2 * H && tid < 3 * H);
    const float kk = istanh ? (-2.f * LOG2E) : (-LOG2E);
    const float aa = istanh ? 2.f : 1.f;
    const float bb = istanh ? -1.f : 0.f;

    float c = 0.f;
    if (tid < H) { h_sh[tid] = h_state[b * H + tid]; c = c_state[b * H + tid]; }
    __syncthreads();
    float h0 = h_sh[lane];
    float h1 = h_sh[64 + lane];

    const long gstride = (long)B * G4;
    const float* __restrict__ gxp = gx + (long)b * G4 + tid;
    float gc = gxp[0];
    float gn = (Tc > 1) ? gxp[gstride] : 0.f;

    uint32_t t0, t1, t2, t3;

    for (int t = 0; t < Tc; ++t) {
        float gn2 = (t + 2 < Tc) ? gxp[(long)(t + 2) * gstride] : 0.f;

        float g0 = gc, g1 = 0.f, g2 = 0.f, g3 = 0.f;

        asm(Q4(0,1,2,3,     "h0","W0","W1","W2","W3")
            Q4(4,5,6,7,     "h0","W4","W5","W6","W7")
            Q4(8,9,10,11,   "h0","W8","W9","W10","W11")
            Q4(12,13,14,15, "h0","W12","W13","W14","W15")
            Q4(16,17,18,19, "h0","W16","W17","W18","W19")
            Q4(20,21,22,23, "h0","W20","W21","W22","W23")
            Q4(24,25,26,27, "h0","W24","W25","W26","W27")
            Q4(28,29,30,31, "h0","W28","W29","W30","W31")
            : [a0]"+v"(g0),[a1]"+v"(g1),[a2]"+v"(g2),[a3]"+v"(g3),
              [t0]"=&s"(t0),[t1]"=&s"(t1),[t2]"=&s"(t2),[t3]"=&s"(t3)
            : [h0]"v"(h0), IN8(0,1,2,3,4,5,6,7), IN8(8,9,10,11,12,13,14,15),
              IN8(16,17,18,19,20,21,22,23), IN8(24,25,26,27,28,29,30,31));

        asm(Q4(32,33,34,35, "h0","W32","W33","W34","W35")
            Q4(36,37,38,39, "h0","W36","W37","W38","W39")
            Q4(40,41,42,43, "h0","W40","W41","W42","W43")
            Q4(44,45,46,47, "h0","W44","W45","W46","W47")
            Q4(48,49,50,51, "h0","W48","W49","W50","W51")
            Q4(52,53,54,55, "h0","W52","W53","W54","W55")
            Q4(56,57,58,59, "h0","W56","W57","W58","W59")
            Q4(60,61,62,63, "h0","W60","W61","W62","W63")
            : [a0]"+v"(g0),[a1]"+v"(g1),[a2]"+v"(g2),[a3]"+v"(g3),
              [t0]"=&s"(t0),[t1]"=&s"(t1),[t2]"=&s"(t2),[t3]"=&s"(t3)
            : [h0]"v"(h0), IN8(32,33,34,35,36,37,38,39), IN8(40,41,42,43,44,45,46,47),
              IN8(48,49,50,51,52,53,54,55), IN8(56,57,58,59,60,61,62,63));

        asm(Q4(0,1,2,3,     "h1","W64","W65","W66","W67")
            Q4(4,5,6,7,     "h1","W68","W69","W70","W71")
            Q4(8,9,10,11,   "h1","W72","W73","W74","W75")
            Q4(12,13,14,15, "h1","W76","W77","W78","W79")
            Q4(16,17,18,19, "h1","W80","W81","W82","W83")
            Q4(20,21,22,23, "h1","W84","W85","W86","W87")
            Q4(24,25,26,27, "h1","W88","W89","W90","W91")
            Q4(28,29,30,31, "h1","W92","W93","W94","W95")
            : [a0]"+v"(g0),[a1]"+v"(g1),[a2]"+v"(g2),[a3]"+v"(g3),
              [t0]"=&s"(t0),[t1]"=&s"(t1),[t2]"=&s"(t2),[t3]"=&s"(t3)
            : [h1]"v"(h1), IN8(64,65,66,67,68,69,70,71), IN8(72,73,74,75,76,77,78,79),
              IN8(80,81,82,83,84,85,86,87), IN8(88,89,90,91,92,93,94,95));

        asm(Q4(32,33,34,35, "h1","W96","W97","W98","W99")
            Q4(36,37,38,39, "h1","W100","W101","W102","W103")
            Q4(40,41,42,43, "h1","W104","W105","W106","W107")
            Q4(44,45,46,47, "h1","W108","W109","W110","W111")
            Q4(48,49,50,51, "h1","W112","W113","W114","W115")
            Q4(52,53,54,55, "h1","W116","W117","W118","W119")
            Q4(56,57,58,59, "h1","W120","W121","W122","W123")
            Q4(60,61,62,63, "h1","W124","W125","W126","W127")
            : [a0]"+v"(g0),[a1]"+v"(g1),[a2]"+v"(g2),[a3]"+v"(g3),
              [t0]"=&s"(t0),[t1]"=&s"(t1),[t2]"=&s"(t2),[t3]"=&s"(t3)
            : [h1]"v"(h1), IN8(96,97,98,99,100,101,102,103), IN8(104,105,106,107,108,109,110,111),
              IN8(112,113,114,115,116,117,118,119), IN8(120,121,122,123,124,125,126,127));

        float g = (g0 + g1) + (g2 + g3);

        float e = __builtin_amdgcn_exp2f(kk * g);
        float s = __builtin_amdgcn_rcpf(1.f + e);
        gates[tid] = fmaf(aa, s, bb);
        __syncthreads();

        if (tid < H) {
            float iv = gates[tid], fv = gates[H + tid], gv = gates[2 * H + tid], ov = gates[3 * H + tid];
            c = fmaf(fv, c, iv * gv);
            float hn = ov * fast_tanh(c);
            h_sh[tid] = hn;
            if (h1c) h1c[(long)b * Tc * H + (long)t * H + tid] = hn;
            if (storeLast && t == Tc - 1) h2last[b * H + tid] = hn;
        }
        __syncthreads();
        h0 = h_sh[lane];
        h1 = h_sh[64 + lane];
        gc = gn; gn = gn2;
    }

    if (tid < H) { h_state[b * H + tid] = h_sh[tid]; c_state[b * H + tid] = c; }
}

// ----------------------------------------------------------------------------
// Dropout: JAX threefry2x32, jax_threefry_partitionable=True (default since
// jax 0.4.36): counter (0, e), bits = y0 ^ y1, key (0, 42).
// ----------------------------------------------------------------------------
__device__ __forceinline__ uint32_t rotl32(uint32_t x, int r) { return (x << r) | (x >> (32 - r)); }

__global__ void dropout_kernel(const float* __restrict__ h2last, float* __restrict__ h2drop)
{
    int e = blockIdx.x * blockDim.x + threadIdx.x;
    if (e >= B * H) return;
    const uint32_t k0 = 0u, k1 = 42u, k2 = 0u ^ 42u ^ 0x1BD11BDAu;
    uint32_t x0 = 0u;
    uint32_t x1 = (uint32_t)e;
    x0 += k0; x1 += k1;
#define RG(ra,rb,rc,rd,ka,kb,inc) \
    x0 += x1; x1 = rotl32(x1, ra); x1 ^= x0; \
    x0 += x1; x1 = rotl32(x1, rb); x1 ^= x0; \
    x0 += x1; x1 = rotl32(x1, rc); x1 ^= x0; \
    x0 += x1; x1 = rotl32(x1, rd); x1 ^= x0; \
    x0 += ka; x1 += kb + inc;
    RG(13,15,26, 6, k1, k2, 1u)
    RG(17,29,16,24, k2, k0, 2u)
    RG(13,15,26, 6, k0, k1, 3u)
    RG(17,29,16,24, k1, k2, 4u)
    RG(13,15,26, 6, k2, k0, 5u)
#undef RG
    uint32_t bits = x0 ^ x1;
    float u = __uint_as_float((bits >> 9) | 0x3f800000u) - 1.0f;
    float a = h2last[e];
    h2drop[e] = (u >= 0.3f) ? (a / 0.7f) : 0.0f;
}

// ----------------------------------------------------------------------------
// Head: out[b][n] = b_out[n] + sum_u h2drop[b][u] * W_out[n][u]
// ----------------------------------------------------------------------------
__global__ void out_kernel(const float* __restrict__ h2drop, const float* __restrict__ W_out,
                           const float* __restrict__ b_out, float* __restrict__ out)
{
    int i = blockIdx.x * blockDim.x + threadIdx.x;
    if (i >= B * 2) return;
    int bb = i >> 1, n = i & 1;
    float acc = b_out[n];
    const float* __restrict__ hp = h2drop + (long)bb * H;
    const float* __restrict__ wp = W_out + (long)n * H;
#pragma unroll 4
    for (int u = 0; u < H; ++u) acc = fmaf(hp[u], wp[u], acc);
    out[i] = acc;
}

// ----------------------------------------------------------------------------
extern "C" void kernel_launch(void* const* d_in, const int* in_sizes, int n_in,
                              void* d_out, int out_size, void* d_ws, size_t ws_size,
                              hipStream_t stream)
{
    const float* x     = (const float*)d_in[0];
    const float* W_ih0 = (const float*)d_in[1];
    const float* W_hh0 = (const float*)d_in[2];
    const float* b_ih0 = (const float*)d_in[3];
    const float* b_hh0 = (const float*)d_in[4];
    const float* W_ih1 = (const float*)d_in[5];
    const float* W_hh1 = (const float*)d_in[6];
    const float* b_ih1 = (const float*)d_in[7];
    const float* b_hh1 = (const float*)d_in[8];
    const float* W_out = (const float*)d_in[9];
    const float* b_out = (const float*)d_in[10];
    float* out = (float*)d_out;

    char* ws = (char*)d_ws;
    size_t off = 0;
    auto alloc = [&](size_t bytes) { void* p = ws + off; off += (bytes + 255) & ~255ull; return p; };

    float* WT0    = (float*)alloc((size_t)FIN * G4 * 4);
    float* WT1    = (float*)alloc((size_t)H * G4 * 4);
    float* bsum0  = (float*)alloc((size_t)G4 * 4);
    float* bsum1  = (float*)alloc((size_t)G4 * 4);
    float* states = (float*)alloc((size_t)4 * B * H * 4);
    float* h0s = states, *c0s = states + B * H, *h1s = states + 2 * B * H, *c1s = states + 3 * B * H;
    float* h2last = (float*)alloc((size_t)B * H * 4);
    float* h2drop = (float*)alloc((size_t)B * H * 4);

    size_t fixed = off;
    int Tc = 16;
    const int cands[7] = {1024, 512, 256, 128, 64, 32, 16};
    for (int ci = 0; ci < 7; ++ci) {
        size_t need = fixed + (size_t)cands[ci] * ((size_t)B * H * 4 + (size_t)B * G4 * 4) + 8192;
        if (need <= ws_size) { Tc = cands[ci]; break; }
    }
    float* h1c = (float*)alloc((size_t)B * Tc * H * 4);
    float* gxb = (float*)alloc((size_t)Tc * B * G4 * 4);

    fprintf(stderr, "[kernel_launch] ws_size=%zu fixed=%zu Tc=%d total_used=%zu\n",
            ws_size, fixed, Tc, off);

    prep_kernel<<<512, 256, 0, stream>>>(W_ih0, b_ih0, b_hh0, W_ih1, b_ih1, b_hh1,
                                         WT0, WT1, bsum0, bsum1, states);

    const int nch = T / Tc;
    for (int c = 0; c < nch; ++c) {
        int t0 = c * Tc;
        gemm_gx<FIN><<<(B * Tc) / 16, 512, 0, stream>>>(x, (long)T * FIN, (long)FIN, t0,
                                                        WT0, bsum0, gxb, Tc);
        lstm_scan<<<B, 512, 0, stream>>>(gxb, W_hh0, h0s, c0s, h1c, nullptr, Tc, 0);
        gemm_gx<H><<<(B * Tc) / 16, 512, 0, stream>>>(h1c, (long)Tc * H, (long)H, 0,
                                                      WT1, bsum1, gxb, Tc);
        lstm_scan<<<B, 512, 0, stream>>>(gxb, W_hh1, h1s, c1s, nullptr, h2last, Tc,
                                         (t0 + Tc == T) ? 1 : 0);
    }

    dropout_kernel<<<128, 256, 0, stream>>>(h2last, h2drop);
    out_kernel<<<2, 256, 0, stream>>>(h2drop, W_out, b_out, out);
}